// Round 2
// baseline (288.814 us; speedup 1.0000x reference)
//
#include <hip/hip_runtime.h>
#include <cmath>
#include <cstdint>

// Shapes (fixed for this problem)
#define BB 4
#define SS 2048
#define EE 1024
#define HH 16
#define DD 64
#define ROWS (BB*SS)          // 8192
#define QKV_N (3*EE)          // 3072
#define NQT 16                // S / 128 q-tiles

using bf16x8 = __attribute__((ext_vector_type(8))) __bf16;
using bf16x4 = __attribute__((ext_vector_type(4))) __bf16;
using f32x4  = __attribute__((ext_vector_type(4))) float;
typedef __attribute__((ext_vector_type(4))) short short4v;

// log2(e) / sqrt(64): folded into Q columns in the QKV GEMM epilogue
#define SCQ 0.18033688f

__device__ inline f32x4 mfma16(bf16x8 a, bf16x8 b, f32x4 c) {
    return __builtin_amdgcn_mfma_f32_16x16x32_bf16(a, b, c, 0, 0, 0);
}

// K=16 MFMA: B-operand layout (k=4*quad+j, n=lane&15) == C/D layout ->
// exp'd S registers feed PV directly, no cross-lane movement. (verified R4/R5/R6)
__device__ inline f32x4 mfma16k16(bf16x4 a, bf16x4 b, f32x4 c) {
    return __builtin_amdgcn_mfma_f32_16x16x16bf16_1k(
        __builtin_bit_cast(short4v, a), __builtin_bit_cast(short4v, b), c, 0, 0, 0);
}

__device__ inline void load_lds16(const void* g, void* l) {
    __builtin_amdgcn_global_load_lds(
        (__attribute__((address_space(1))) void*)g,
        (__attribute__((address_space(3))) void*)l, 16, 0, 0);
}

// raw barrier + counted vmcnt (compiler memory fences; MFMA may drift, regs are safe)
#define BAR()   asm volatile("s_barrier" ::: "memory")
#define VMW(n)  asm volatile("s_waitcnt vmcnt(" #n ")" ::: "memory")

// ---------------- cast fp32 -> bf16, vectorized ----------------
__global__ __launch_bounds__(256) void cast_f32_bf16(const float* __restrict__ in,
                                                     __bf16* __restrict__ out) {
    size_t i = ((size_t)blockIdx.x * 256 + threadIdx.x) * 4;
    float4 v = *(const float4*)(in + i);
    bf16x4 o;
    o[0] = (__bf16)v.x; o[1] = (__bf16)v.y; o[2] = (__bf16)v.z; o[3] = (__bf16)v.w;
    *(bf16x4*)(out + i) = o;
}

// ---------------- transpose + cast: in [K][N] f32 -> out [N][K] bf16 ----------------
__global__ __launch_bounds__(256) void transpose_cast(const float* __restrict__ in,
                                                      __bf16* __restrict__ out,
                                                      int K, int N) {
    __shared__ float tile[32][33];
    int n0 = blockIdx.x * 32, k0 = blockIdx.y * 32;
    int tx = threadIdx.x, ty = threadIdx.y;   // block (32,8)
#pragma unroll
    for (int i = 0; i < 4; ++i)
        tile[ty + 8 * i][tx] = in[(size_t)(k0 + ty + 8 * i) * N + n0 + tx];
    __syncthreads();
#pragma unroll
    for (int i = 0; i < 4; ++i)
        out[(size_t)(n0 + ty + 8 * i) * K + k0 + tx] = (__bf16)tile[tx][ty + 8 * i];
}

// ---------------- V transpose: qkv V-section -> vt[b][h][d][s] bf16 ----------------
__global__ __launch_bounds__(256) void build_vt(const __bf16* __restrict__ qkv,
                                                __bf16* __restrict__ vt) {
    __shared__ __bf16 tile[64 * 72];   // [s][d] padded
    const int s0 = blockIdx.x * 64, h = blockIdx.y, b = blockIdx.z;
    const int tid = threadIdx.x;
#pragma unroll
    for (int r = 0; r < 2; ++r) {
        int c = r * 256 + tid;                 // 0..511
        int s = c >> 3, dp = c & 7;
        bf16x8 v = *(const bf16x8*)(qkv + (size_t)(b * SS + s0 + s) * QKV_N + 2048 + h * 64 + dp * 8);
        *(bf16x8*)(tile + s * 72 + dp * 8) = v;
    }
    __syncthreads();
#pragma unroll
    for (int r = 0; r < 2; ++r) {
        int c = r * 256 + tid;
        int d = c >> 3, sp = c & 7;
        bf16x8 o;
#pragma unroll
        for (int i = 0; i < 8; ++i) o[i] = tile[(sp * 8 + i) * 72 + d];
        *(bf16x8*)(vt + (size_t)((b * HH + h) * 64 + d) * SS + s0 + sp * 8) = o;
    }
}

// ================= 256x256 8-wave deep-pipelined GEMM =================
// C[M][N] = A[M][K] @ Bt[N][K]^T + bias.  BK=64, 512 threads (2M x 4N waves),
// per-wave 128x64 output (acc[8][4]), LDS 128 KB (2 bufs x (A+B) 256x64 bf16).
// Schedule per K-tile T (4 phases, one C-quadrant each, 16 MFMA/phase):
//   c0: ds_read A(mi0-3)+B(ni0-1) [12]; stage A1(T+1); BAR; MFMA Q00; BAR
//   c1: ds_read B(ni2-3) [4];          stage B0(T+1); BAR; MFMA Q01; BAR
//   c2: ds_read A(mi4-7) [8];          stage B1(T+1); BAR; MFMA Q11; BAR
//   c3:                                 stage A0(T+2); BAR; MFMA Q10; vmcnt(2); BAR
// Safety: buffer buf[T&1] is fully read by end of c2 (every frag consumed by the
// same phase's MFMA -> compiler's lgkmcnt drains reads before that phase's end
// barrier), so c3 may begin overwriting it for tile T+2. vmcnt(2) at c3 retires
// everything except the just-issued half-tile -> tile T+1 (staged c3(T-1)..c2(T))
// is complete before c0(T+1)'s ds_reads. Tail (T+2>=NT): vmcnt(0) (the counted
// form would otherwise let tile T+1's last half stay in flight).
// LDS swizzle: 16B slot ^= (row&7), applied on the pre-swizzled GLOBAL source
// (global_load_lds dest must be linear) and on the ds_read side (rule #21).
__device__ __forceinline__ void stage_half(const __bf16* __restrict__ src, size_t ldk,
                                           int rowbase, int k0, __bf16* dst, int tid) {
#pragma unroll
    for (int r = 0; r < 2; ++r) {
        int cc = r * 512 + tid;                 // 0..1023 : 128 rows x 8 slots
        int row = cc >> 3, slot = cc & 7;
        load_lds16(src + (size_t)(rowbase + row) * ldk + k0 + ((slot ^ (row & 7)) << 3),
                   dst + cc * 8);
    }
}

__device__ __forceinline__ bf16x8 ldfrag(const __bf16* base, int row, int slot) {
    return *(const bf16x8*)(base + row * 64 + ((slot ^ (row & 7)) << 3));
}

template <bool OUT_BF16, bool QSCALE>
__global__ __launch_bounds__(512, 2) void gemm8p(const __bf16* __restrict__ A,
                                                 const __bf16* __restrict__ Bt,
                                                 const float* __restrict__ bias,
                                                 void* __restrict__ Cout,
                                                 int M, int N, int K, int nbm) {
    __shared__ __bf16 Alds[2][256 * 64];
    __shared__ __bf16 Blds[2][256 * 64];
    const int tid  = threadIdx.x;
    const int wave = tid >> 6, lane = tid & 63;
    const int lrow = lane & 15, quad = lane >> 4;
    const int wm = wave >> 2;                  // 0..1  -> rows wm*128
    const int wn = wave & 3;                   // 0..3  -> cols wn*64
    // XCD-bijective block swizzle (gridDim.x % 8 == 0 guaranteed by launch)
    const int nwg = gridDim.x, id = blockIdx.x;
    const int vid = (id & 7) * (nwg >> 3) + (id >> 3);
    const int tm = (vid % nbm) * 256;
    const int tn = (vid / nbm) * 256;
    const int NT = K >> 6;

    f32x4 acc[8][4] = {};

    // prologue: tile0 fully + A0(tile1); wait tile0 (allow tile1's 2 loads)
    stage_half(A,  K, tm,       0, Alds[0],        tid);
    stage_half(A,  K, tm + 128, 0, Alds[0] + 8192, tid);
    stage_half(Bt, K, tn,       0, Blds[0],        tid);
    stage_half(Bt, K, tn + 128, 0, Blds[0] + 8192, tid);
    stage_half(A,  K, tm,      64, Alds[1],        tid);
    VMW(2);
    BAR();

    for (int T = 0; T < NT; ++T) {
        const int cur = T & 1, nxt = cur ^ 1;
        const __bf16* Ab = Alds[cur];
        const __bf16* Bb = Blds[cur];
        const int k1 = (T + 1) * 64, k2 = (T + 2) * 64;
        bf16x8 af[4][2], bf[4][2];

        // ---- phase c0 : Q(0,0) ----
#pragma unroll
        for (int mi = 0; mi < 4; ++mi)
#pragma unroll
            for (int ks = 0; ks < 2; ++ks)
                af[mi][ks] = ldfrag(Ab, wm * 128 + mi * 16 + lrow, quad + 4 * ks);
#pragma unroll
        for (int ni = 0; ni < 2; ++ni)
#pragma unroll
            for (int ks = 0; ks < 2; ++ks)
                bf[ni][ks] = ldfrag(Bb, wn * 64 + ni * 16 + lrow, quad + 4 * ks);
        if (T + 1 < NT) stage_half(A, K, tm + 128, k1, Alds[nxt] + 8192, tid);
        BAR();
        __builtin_amdgcn_s_setprio(1);
#pragma unroll
        for (int mi = 0; mi < 4; ++mi)
#pragma unroll
            for (int ni = 0; ni < 2; ++ni)
#pragma unroll
                for (int ks = 0; ks < 2; ++ks)
                    acc[mi][ni] = mfma16(af[mi][ks], bf[ni][ks], acc[mi][ni]);
        __builtin_amdgcn_s_setprio(0);
        BAR();

        // ---- phase c1 : Q(0,1) ----
#pragma unroll
        for (int ni = 0; ni < 2; ++ni)
#pragma unroll
            for (int ks = 0; ks < 2; ++ks)
                bf[2 + ni][ks] = ldfrag(Bb, wn * 64 + (2 + ni) * 16 + lrow, quad + 4 * ks);
        if (T + 1 < NT) stage_half(Bt, K, tn, k1, Blds[nxt], tid);
        BAR();
        __builtin_amdgcn_s_setprio(1);
#pragma unroll
        for (int mi = 0; mi < 4; ++mi)
#pragma unroll
            for (int ni = 0; ni < 2; ++ni)
#pragma unroll
                for (int ks = 0; ks < 2; ++ks)
                    acc[mi][2 + ni] = mfma16(af[mi][ks], bf[2 + ni][ks], acc[mi][2 + ni]);
        __builtin_amdgcn_s_setprio(0);
        BAR();

        // ---- phase c2 : Q(1,1) ----  (af[] now re-loaded with mi4-7)
#pragma unroll
        for (int mi = 0; mi < 4; ++mi)
#pragma unroll
            for (int ks = 0; ks < 2; ++ks)
                af[mi][ks] = ldfrag(Ab, wm * 128 + (4 + mi) * 16 + lrow, quad + 4 * ks);
        if (T + 1 < NT) stage_half(Bt, K, tn + 128, k1, Blds[nxt] + 8192, tid);
        BAR();
        __builtin_amdgcn_s_setprio(1);
#pragma unroll
        for (int mi = 0; mi < 4; ++mi)
#pragma unroll
            for (int ni = 0; ni < 2; ++ni)
#pragma unroll
                for (int ks = 0; ks < 2; ++ks)
                    acc[4 + mi][2 + ni] = mfma16(af[mi][ks], bf[2 + ni][ks], acc[4 + mi][2 + ni]);
        __builtin_amdgcn_s_setprio(0);
        BAR();

        // ---- phase c3 : Q(1,0) ----
        const bool st = (T + 2 < NT);
        if (st) stage_half(A, K, tm, k2, Alds[cur], tid);
        BAR();
        __builtin_amdgcn_s_setprio(1);
#pragma unroll
        for (int mi = 0; mi < 4; ++mi)
#pragma unroll
            for (int ni = 0; ni < 2; ++ni)
#pragma unroll
                for (int ks = 0; ks < 2; ++ks)
                    acc[4 + mi][ni] = mfma16(af[mi][ks], bf[ni][ks], acc[4 + mi][ni]);
        __builtin_amdgcn_s_setprio(0);
        if (st) { VMW(2); } else { VMW(0); }
        BAR();
    }

    // epilogue
#pragma unroll
    for (int ni = 0; ni < 4; ++ni) {
        int cn = tn + wn * 64 + ni * 16 + lrow;
        float bv = bias[cn];
        float sc = (QSCALE && cn < EE) ? SCQ : 1.0f;
#pragma unroll
        for (int mi = 0; mi < 8; ++mi) {
#pragma unroll
            for (int r = 0; r < 4; ++r) {
                int gm = tm + wm * 128 + mi * 16 + quad * 4 + r;
                float v = (acc[mi][ni][r] + bv) * sc;
                if (OUT_BF16)
                    ((__bf16*)Cout)[(size_t)gm * N + cn] = (__bf16)v;
                else
                    ((float*)Cout)[(size_t)gm * N + cn] = v;
            }
        }
    }
}

// stage one 64-key K tile + V^T tile into the given LDS buffers (XOR-swizzled
// via pre-swizzled GLOBAL source, LDS dest linear per global_load_lds rules)
__device__ __forceinline__ void stage_kv64(const __bf16* __restrict__ kbase,
                                           const __bf16* __restrict__ vbase,
                                           __bf16* Kb, __bf16* Vb, int kb, int tid) {
#pragma unroll
    for (int r = 0; r < 2; ++r) {          // K: 64 rows x 64 d
        int c = r * 256 + tid;
        int row = c >> 3;
        int g8 = ((c & 7) ^ (row & 7)) * 8;
        load_lds16(kbase + (size_t)(kb + row) * QKV_N + g8, Kb + c * 8);
    }
#pragma unroll
    for (int r = 0; r < 2; ++r) {          // V^T: 64 d-rows x 64 keys
        int c = r * 256 + tid;
        int d = c >> 3, kc = c & 7;
        int g8 = (kc ^ (d & 7)) * 8;
        load_lds16(vbase + (size_t)d * SS + kb + g8, Vb + c * 8);
    }
}

// ---------------- Flash attention v8 (unchanged from R1) ----------------
__global__ __launch_bounds__(256, 4) void attn8(const __bf16* __restrict__ qkv,
                                                const __bf16* __restrict__ vt,
                                                __bf16* __restrict__ y) {
    const int hb = blockIdx.x;                 // fast dim: h + 16*b -> XCD = hb%8
    const int h = hb & 15, b = hb >> 4;
    const int j = blockIdx.y;                  // 0..15
    const int r4 = j & 3, s4 = j >> 2;
    // classes {15,0,8,7} {14,1,9,6} {13,2,10,5} {12,3,11,4}: each sums 30
    const int qt = (s4 == 0) ? 15 - r4 : (s4 == 1) ? r4 : (s4 == 2) ? 8 + r4 : 7 - r4;

    const int tid = threadIdx.x;
    const int wave = tid >> 6, lane = tid & 63;
    const int lrow = lane & 15, quad = lane >> 4;
    const int lm7 = lrow & 7;

    __shared__ __bf16 Klds[2][64 * 64];   // [key][d-chunk8 ^ (key&7)]   2x8 KB
    __shared__ __bf16 Vlds[2][64 * 64];   // [d][k-chunk8 ^ (d&7)]       2x8 KB

    const __bf16* kbase = qkv + (size_t)b * SS * QKV_N + 1024 + h * 64;
    const __bf16* vbase = vt + (size_t)(b * HH + h) * 64 * SS;

    const int qbase = qt * 128;
    // Q fragments (B-operand): q col = lrow; group g -> rows qbase+64g+16w+lrow
    bf16x8 qf[2][2];
#pragma unroll
    for (int g = 0; g < 2; ++g) {
        const __bf16* qp = qkv + (size_t)(b * SS + qbase + 64 * g + wave * 16 + lrow) * QKV_N + h * 64;
        qf[g][0] = *(const bf16x8*)(qp + quad * 8);
        qf[g][1] = *(const bf16x8*)(qp + 32 + quad * 8);
    }
    const int q0 = qbase + wave * 16 + lrow;

    float m[2] = {-INFINITY, -INFINITY};
    float l[2] = {0.f, 0.f};                   // lane-partial row sums
    f32x4 oacc[2][4] = {};   // O^T: d = 16*td + 4*quad + r, q col = lrow

    const int nkv = 2 * qt + 2;                // 64-key blocks
    stage_kv64(kbase, vbase, Klds[0], Vlds[0], 0, tid);   // prime buffer 0

    for (int kk = 0; kk < nkv; ++kk) {
        const int cur = kk & 1;
        const int kb = kk * 64;
        __syncthreads();   // buf[cur] staged; all waves done with buf[cur^1]
        if (kk + 1 < nkv)
            stage_kv64(kbase, vbase, Klds[cur ^ 1], Vlds[cur ^ 1], kb + 64, tid);
        const __bf16* Kb = Klds[cur];
        const __bf16* Vb = Vlds[cur];

        const bool do0 = (kk < nkv - 1);       // last block fully masked for group0
        const bool dg0 = (kk == nkv - 2);      // group0 diagonal block
        const bool dg1 = (kk == nkv - 1);      // group1 diagonal block

        // QK^T: 4 key tiles of 16
        f32x4 s0[4], s1[4];
#pragma unroll
        for (int t = 0; t < 4; ++t) {
            const __bf16* kr = Kb + (16 * t + lrow) * 64;
            bf16x8 kf0 = *(const bf16x8*)(kr + 8 * (quad ^ lm7));
            bf16x8 kf1 = *(const bf16x8*)(kr + 8 * ((4 + quad) ^ lm7));
            f32x4 c1 = {};
            c1 = mfma16(kf0, qf[1][0], c1);
            c1 = mfma16(kf1, qf[1][1], c1);
            s1[t] = c1;
            if (do0) {
                f32x4 c0 = {};
                c0 = mfma16(kf0, qf[0][0], c0);
                c0 = mfma16(kf1, qf[0][1], c0);
                s0[t] = c0;
            }
        }
        if (dg0) {
#pragma unroll
            for (int t = 0; t < 4; ++t)
#pragma unroll
                for (int r = 0; r < 4; ++r)
                    if (kb + 16 * t + 4 * quad + r > q0) s0[t][r] = -INFINITY;
        }
        if (dg1) {
#pragma unroll
            for (int t = 0; t < 4; ++t)
#pragma unroll
                for (int r = 0; r < 4; ++r)
                    if (kb + 16 * t + 4 * quad + r > q0 + 64) s1[t][r] = -INFINITY;
        }

        // online softmax with deferred max (THR=8), per group
        bf16x4 p0[4], p1[4];
#pragma unroll
        for (int g = 0; g < 2; ++g) {
            if (g == 0 && !do0) continue;
            f32x4* s = g ? s1 : s0;
            bf16x4* p = g ? p1 : p0;
            float pmax = -INFINITY;
#pragma unroll
            for (int t = 0; t < 4; ++t)
                pmax = fmaxf(pmax, fmaxf(fmaxf(s[t][0], s[t][1]), fmaxf(s[t][2], s[t][3])));
            // NaN (first iter -inf - -inf) compares false -> triggers rescale
            if (!__all(pmax - m[g] <= 8.0f)) {
                float mr = fmaxf(pmax, __shfl_xor(pmax, 16));
                mr = fmaxf(mr, __shfl_xor(mr, 32));
                float mnew = fmaxf(m[g], mr);
                float alpha = exp2f(m[g] - mnew);
                m[g] = mnew;
                l[g] *= alpha;
#pragma unroll
                for (int td = 0; td < 4; ++td) {
                    oacc[g][td][0] *= alpha; oacc[g][td][1] *= alpha;
                    oacc[g][td][2] *= alpha; oacc[g][td][3] *= alpha;
                }
            }
            const float mg = m[g];
#pragma unroll
            for (int t = 0; t < 4; ++t) {
                float e0 = exp2f(s[t][0] - mg);
                float e1 = exp2f(s[t][1] - mg);
                float e2 = exp2f(s[t][2] - mg);
                float e3 = exp2f(s[t][3] - mg);
                l[g] += (e0 + e1) + (e2 + e3);
                p[t][0] = (__bf16)e0; p[t][1] = (__bf16)e1;
                p[t][2] = (__bf16)e2; p[t][3] = (__bf16)e3;
            }
        }

        // PV: O^T += V^T P^T, K=16 per key tile; V frags shared across groups
#pragma unroll
        for (int t = 0; t < 4; ++t) {
            int klog = 2 * t + (quad >> 1);
            int c8 = klog ^ lm7;
            const __bf16* vcol = Vb + (size_t)lrow * 64 + c8 * 8 + 4 * (quad & 1);
#pragma unroll
            for (int td = 0; td < 4; ++td) {
                bf16x4 vf = *(const bf16x4*)(vcol + td * 16 * 64);
                oacc[1][td] = mfma16k16(vf, p1[t], oacc[1][td]);
                if (do0) oacc[0][td] = mfma16k16(vf, p0[t], oacc[0][td]);
            }
        }
    }

    // epilogue: reduce lane-partial l over quads, then write
#pragma unroll
    for (int g = 0; g < 2; ++g) {
        float lr = l[g];
        lr += __shfl_xor(lr, 16);
        lr += __shfl_xor(lr, 32);
        float linv = 1.f / lr;
        __bf16* yp = y + (size_t)(b * SS + qbase + 64 * g + wave * 16 + lrow) * EE + h * 64;
#pragma unroll
        for (int td = 0; td < 4; ++td) {
            bf16x4 o;
#pragma unroll
            for (int r = 0; r < 4; ++r) o[r] = (__bf16)(oacc[g][td][r] * linv);
            *(bf16x4*)(yp + 16 * td + 4 * quad) = o;
        }
    }
}

// ---------------- launch ----------------
extern "C" void kernel_launch(void* const* d_in, const int* in_sizes, int n_in,
                              void* d_out, int out_size, void* d_ws, size_t ws_size,
                              hipStream_t stream) {
    const float* x      = (const float*)d_in[0];
    const float* w_qkv  = (const float*)d_in[1];
    const float* b_qkv  = (const float*)d_in[2];
    const float* w_proj = (const float*)d_in[3];
    const float* b_proj = (const float*)d_in[4];
    float* out = (float*)d_out;

    __bf16* xb     = (__bf16*)d_ws;                      // 16 MB (reused as vt later)
    __bf16* wqkvT  = xb + (size_t)ROWS * EE;             // [3072][1024]
    __bf16* wprojT = wqkvT + (size_t)QKV_N * EE;         // [1024][1024]
    __bf16* qkv    = wprojT + (size_t)EE * EE;           // [8192][3072]
    __bf16* yb     = qkv + (size_t)ROWS * QKV_N;         // [8192][1024]
    __bf16* vtb    = xb;                                 // alias: xb dead after GEMM1

    cast_f32_bf16<<<dim3(ROWS * EE / 1024), dim3(256), 0, stream>>>(x, xb);
    transpose_cast<<<dim3(QKV_N / 32, EE / 32), dim3(32, 8), 0, stream>>>(w_qkv, wqkvT, EE, QKV_N);
    transpose_cast<<<dim3(EE / 32, EE / 32), dim3(32, 8), 0, stream>>>(w_proj, wprojT, EE, EE);
    // 256x256 tiles: gemm1 grid 32x12=384, gemm2 grid 32x4=128 (both %8==0)
    gemm8p<true, true><<<dim3((ROWS / 256) * (QKV_N / 256)), dim3(512), 0, stream>>>(
        xb, wqkvT, b_qkv, (void*)qkv, ROWS, QKV_N, EE, ROWS / 256);
    build_vt<<<dim3(SS / 64, HH, BB), dim3(256), 0, stream>>>(qkv, vtb);
    attn8<<<dim3(HH * BB, NQT), dim3(256), 0, stream>>>(qkv, vtb, yb);
    gemm8p<false, false><<<dim3((ROWS / 256) * (EE / 256)), dim3(512), 0, stream>>>(
        yb, wprojT, b_proj, (void*)out, ROWS, EE, EE, ROWS / 256);
}

// Round 3
// 286.073 us; speedup vs baseline: 1.0096x; 1.0096x over previous
//
#include <hip/hip_runtime.h>
#include <cmath>
#include <cstdint>

// Shapes (fixed for this problem)
#define BB 4
#define SS 2048
#define EE 1024
#define HH 16
#define DD 64
#define ROWS (BB*SS)          // 8192
#define QKV_N (3*EE)          // 3072
#define NQT 16                // S / 128 q-tiles

using bf16x8 = __attribute__((ext_vector_type(8))) __bf16;
using bf16x4 = __attribute__((ext_vector_type(4))) __bf16;
using f32x4  = __attribute__((ext_vector_type(4))) float;
typedef __attribute__((ext_vector_type(4))) short short4v;

// log2(e) / sqrt(64): folded into Q columns in the QKV GEMM epilogue
#define SCQ 0.18033688f

__device__ inline f32x4 mfma16(bf16x8 a, bf16x8 b, f32x4 c) {
    return __builtin_amdgcn_mfma_f32_16x16x32_bf16(a, b, c, 0, 0, 0);
}

// K=16 MFMA: B-operand layout (k=4*quad+j, n=lane&15) == C/D layout ->
// exp'd S registers feed PV directly, no cross-lane movement. (verified R4/R5/R6)
__device__ inline f32x4 mfma16k16(bf16x4 a, bf16x4 b, f32x4 c) {
    return __builtin_amdgcn_mfma_f32_16x16x16bf16_1k(
        __builtin_bit_cast(short4v, a), __builtin_bit_cast(short4v, b), c, 0, 0, 0);
}

__device__ inline void load_lds16(const void* g, void* l) {
    __builtin_amdgcn_global_load_lds(
        (__attribute__((address_space(1))) void*)g,
        (__attribute__((address_space(3))) void*)l, 16, 0, 0);
}

// raw barrier + counted vmcnt (compiler memory fences)
#define BAR()   asm volatile("s_barrier" ::: "memory")
#define VMW(n)  asm volatile("s_waitcnt vmcnt(" #n ")" ::: "memory")

// ---------------- cast fp32 -> bf16, vectorized ----------------
__global__ __launch_bounds__(256) void cast_f32_bf16(const float* __restrict__ in,
                                                     __bf16* __restrict__ out) {
    size_t i = ((size_t)blockIdx.x * 256 + threadIdx.x) * 4;
    float4 v = *(const float4*)(in + i);
    bf16x4 o;
    o[0] = (__bf16)v.x; o[1] = (__bf16)v.y; o[2] = (__bf16)v.z; o[3] = (__bf16)v.w;
    *(bf16x4*)(out + i) = o;
}

// ---------------- transpose + cast: in [K][N] f32 -> out [N][K] bf16 ----------------
__global__ __launch_bounds__(256) void transpose_cast(const float* __restrict__ in,
                                                      __bf16* __restrict__ out,
                                                      int K, int N) {
    __shared__ float tile[32][33];
    int n0 = blockIdx.x * 32, k0 = blockIdx.y * 32;
    int tx = threadIdx.x, ty = threadIdx.y;   // block (32,8)
#pragma unroll
    for (int i = 0; i < 4; ++i)
        tile[ty + 8 * i][tx] = in[(size_t)(k0 + ty + 8 * i) * N + n0 + tx];
    __syncthreads();
#pragma unroll
    for (int i = 0; i < 4; ++i)
        out[(size_t)(n0 + ty + 8 * i) * K + k0 + tx] = (__bf16)tile[tx][ty + 8 * i];
}

// ---------------- V transpose: qkv V-section -> vt[b][h][d][s] bf16 ----------------
__global__ __launch_bounds__(256) void build_vt(const __bf16* __restrict__ qkv,
                                                __bf16* __restrict__ vt) {
    __shared__ __bf16 tile[64 * 72];   // [s][d] padded
    const int s0 = blockIdx.x * 64, h = blockIdx.y, b = blockIdx.z;
    const int tid = threadIdx.x;
#pragma unroll
    for (int r = 0; r < 2; ++r) {
        int c = r * 256 + tid;                 // 0..511
        int s = c >> 3, dp = c & 7;
        bf16x8 v = *(const bf16x8*)(qkv + (size_t)(b * SS + s0 + s) * QKV_N + 2048 + h * 64 + dp * 8);
        *(bf16x8*)(tile + s * 72 + dp * 8) = v;
    }
    __syncthreads();
#pragma unroll
    for (int r = 0; r < 2; ++r) {
        int c = r * 256 + tid;
        int d = c >> 3, sp = c & 7;
        bf16x8 o;
#pragma unroll
        for (int i = 0; i < 8; ++i) o[i] = tile[(sp * 8 + i) * 72 + d];
        *(bf16x8*)(vt + (size_t)((b * HH + h) * 64 + d) * SS + s0 + sp * 8) = o;
    }
}

// ================= 256x128 8-wave deep-pipelined GEMM (v2) =================
// C[M][N] = A[M][K] @ Bt[N][K]^T + bias.  BK=64, 512 threads (4M x 2N waves),
// per-wave 64x64 output (acc[4][4]), LDS 96 KB (2 bufs x (A 256x64 + B 128x64)).
// Geometry fixes vs R2: grids are exact CU multiples (768 = 3.0 rounds,
// 256 = 1.0), and block->tile mapping keeps each XCD on 4 fixed M-tiles
// (A panel 2 MB resident in its L2) sweeping N (B slice 2 MB) -> working
// set fits 4 MB L2 (R2's mapping streamed all of A per XCD: FETCH 103 MB).
// Schedule per K-tile T (4 phases, 8 MFMA each):
//   c0: ds_read af(mi0-1)+bf(ni0-3) [12]; stage A1(T+1); BAR; MFMA Q0* lo; BAR
//   c1: ds_read (none extra);             stage B(T+1);  BAR; MFMA Q0* hi; BAR
//   c2: ds_read af(mi2-3) [4];                           BAR; MFMA Q1* hi; BAR
//   c3: stage A0(T+2) into buf[cur];      BAR; MFMA Q1* lo; vmcnt(2|0); BAR
// vmcnt invariant: after c3's VMW(2), only A0(T+2)'s 2 loads remain in
// flight; tile T+1 (A0 staged at c3(T-1), A1 at c0(T), B at c1(T)) is
// complete before c0(T+1)'s ds_reads. Tail uses vmcnt(0).
// LDS swizzle: 16B slot ^= (row&7) on the pre-swizzled GLOBAL source
// (global_load_lds dest linear) and on the ds_read side (rule #21).
__device__ __forceinline__ void stage_half(const __bf16* __restrict__ src, size_t ldk,
                                           int rowbase, int k0, __bf16* dst, int tid) {
#pragma unroll
    for (int r = 0; r < 2; ++r) {
        int cc = r * 512 + tid;                 // 0..1023 : 128 rows x 8 slots
        int row = cc >> 3, slot = cc & 7;
        load_lds16(src + (size_t)(rowbase + row) * ldk + k0 + ((slot ^ (row & 7)) << 3),
                   dst + cc * 8);
    }
}

__device__ __forceinline__ bf16x8 ldfrag(const __bf16* base, int row, int slot) {
    return *(const bf16x8*)(base + row * 64 + ((slot ^ (row & 7)) << 3));
}

template <bool OUT_BF16, bool QSCALE>
__global__ __launch_bounds__(512, 2) void gemm8p(const __bf16* __restrict__ A,
                                                 const __bf16* __restrict__ Bt,
                                                 const float* __restrict__ bias,
                                                 void* __restrict__ Cout,
                                                 int M, int N, int K) {
    __shared__ __bf16 Alds[2][256 * 64];
    __shared__ __bf16 Blds[2][128 * 64];
    const int tid  = threadIdx.x;
    const int wave = tid >> 6, lane = tid & 63;
    const int lrow = lane & 15, quad = lane >> 4;
    const int wm = wave >> 1;                  // 0..3 -> A rows wm*64
    const int wn = wave & 1;                   // 0..1 -> B rows wn*64
    // per-XCD M-residency mapping: XCD (id%8) owns mtpx consecutive M-tiles
    // for the whole kernel and sweeps N -> A panel stays L2-resident.
    const int id = blockIdx.x;
    const int xcd = id & 7, w = id >> 3;
    const int mtpx = (M >> 8) >> 3;            // M-tiles per XCD (4 here)
    const int tm = (mtpx * xcd + (w % mtpx)) * 256;
    const int tn = (w / mtpx) * 128;
    const int NT = K >> 6;

    f32x4 acc[4][4] = {};

    // prologue: tile0 (A0,A1,B) + A0(tile1); wait tile0, leave A0(T1) in flight
    stage_half(A,  K, tm,       0, Alds[0],        tid);
    stage_half(A,  K, tm + 128, 0, Alds[0] + 8192, tid);
    stage_half(Bt, K, tn,       0, Blds[0],        tid);
    stage_half(A,  K, tm,      64, Alds[1],        tid);
    VMW(2);
    BAR();

    for (int T = 0; T < NT; ++T) {
        const int cur = T & 1, nxt = cur ^ 1;
        const __bf16* Ab = Alds[cur];
        const __bf16* Bb = Blds[cur];
        const int k1 = (T + 1) * 64, k2 = (T + 2) * 64;
        const bool pf = (T + 1 < NT);
        bf16x8 af[2][2], bf[4][2];

        // ---- phase c0 : mi0-1 x ni0-1 ----
#pragma unroll
        for (int mi = 0; mi < 2; ++mi)
#pragma unroll
            for (int ks = 0; ks < 2; ++ks)
                af[mi][ks] = ldfrag(Ab, wm * 64 + mi * 16 + lrow, quad + 4 * ks);
#pragma unroll
        for (int ni = 0; ni < 4; ++ni)
#pragma unroll
            for (int ks = 0; ks < 2; ++ks)
                bf[ni][ks] = ldfrag(Bb, wn * 64 + ni * 16 + lrow, quad + 4 * ks);
        if (pf) stage_half(A, K, tm + 128, k1, Alds[nxt] + 8192, tid);
        BAR();
        __builtin_amdgcn_s_setprio(1);
#pragma unroll
        for (int mi = 0; mi < 2; ++mi)
#pragma unroll
            for (int ni = 0; ni < 2; ++ni)
#pragma unroll
                for (int ks = 0; ks < 2; ++ks)
                    acc[mi][ni] = mfma16(af[mi][ks], bf[ni][ks], acc[mi][ni]);
        __builtin_amdgcn_s_setprio(0);
        BAR();

        // ---- phase c1 : mi0-1 x ni2-3 ----
        if (pf) stage_half(Bt, K, tn, k1, Blds[nxt], tid);
        BAR();
        __builtin_amdgcn_s_setprio(1);
#pragma unroll
        for (int mi = 0; mi < 2; ++mi)
#pragma unroll
            for (int ni = 0; ni < 2; ++ni)
#pragma unroll
                for (int ks = 0; ks < 2; ++ks)
                    acc[mi][2 + ni] = mfma16(af[mi][ks], bf[2 + ni][ks], acc[mi][2 + ni]);
        __builtin_amdgcn_s_setprio(0);
        BAR();

        // ---- phase c2 : mi2-3 x ni2-3 (af reloaded) ----
#pragma unroll
        for (int mi = 0; mi < 2; ++mi)
#pragma unroll
            for (int ks = 0; ks < 2; ++ks)
                af[mi][ks] = ldfrag(Ab, wm * 64 + (2 + mi) * 16 + lrow, quad + 4 * ks);
        BAR();
        __builtin_amdgcn_s_setprio(1);
#pragma unroll
        for (int mi = 0; mi < 2; ++mi)
#pragma unroll
            for (int ni = 0; ni < 2; ++ni)
#pragma unroll
                for (int ks = 0; ks < 2; ++ks)
                    acc[2 + mi][2 + ni] = mfma16(af[mi][ks], bf[2 + ni][ks], acc[2 + mi][2 + ni]);
        __builtin_amdgcn_s_setprio(0);
        BAR();

        // ---- phase c3 : mi2-3 x ni0-1 ----
        const bool st = (T + 2 < NT);
        if (st) stage_half(A, K, tm, k2, Alds[cur], tid);
        BAR();
        __builtin_amdgcn_s_setprio(1);
#pragma unroll
        for (int mi = 0; mi < 2; ++mi)
#pragma unroll
            for (int ni = 0; ni < 2; ++ni)
#pragma unroll
                for (int ks = 0; ks < 2; ++ks)
                    acc[2 + mi][ni] = mfma16(af[mi][ks], bf[ni][ks], acc[2 + mi][ni]);
        __builtin_amdgcn_s_setprio(0);
        if (st) { VMW(2); } else { VMW(0); }
        BAR();
    }

    // epilogue
#pragma unroll
    for (int ni = 0; ni < 4; ++ni) {
        int cn = tn + wn * 64 + ni * 16 + lrow;
        float bv = bias[cn];
        float sc = (QSCALE && cn < EE) ? SCQ : 1.0f;
#pragma unroll
        for (int mi = 0; mi < 4; ++mi) {
#pragma unroll
            for (int r = 0; r < 4; ++r) {
                int gm = tm + wm * 64 + mi * 16 + quad * 4 + r;
                float v = (acc[mi][ni][r] + bv) * sc;
                if (OUT_BF16)
                    ((__bf16*)Cout)[(size_t)gm * N + cn] = (__bf16)v;
                else
                    ((float*)Cout)[(size_t)gm * N + cn] = v;
            }
        }
    }
}

// stage one 64-key K tile + V^T tile into the given LDS buffers (XOR-swizzled
// via pre-swizzled GLOBAL source, LDS dest linear per global_load_lds rules)
__device__ __forceinline__ void stage_kv64(const __bf16* __restrict__ kbase,
                                           const __bf16* __restrict__ vbase,
                                           __bf16* Kb, __bf16* Vb, int kb, int tid) {
#pragma unroll
    for (int r = 0; r < 2; ++r) {          // K: 64 rows x 64 d
        int c = r * 256 + tid;
        int row = c >> 3;
        int g8 = ((c & 7) ^ (row & 7)) * 8;
        load_lds16(kbase + (size_t)(kb + row) * QKV_N + g8, Kb + c * 8);
    }
#pragma unroll
    for (int r = 0; r < 2; ++r) {          // V^T: 64 d-rows x 64 keys
        int c = r * 256 + tid;
        int d = c >> 3, kc = c & 7;
        int g8 = (kc ^ (d & 7)) * 8;
        load_lds16(vbase + (size_t)d * SS + kb + g8, Vb + c * 8);
    }
}

// ---------------- Flash attention v8 (unchanged) ----------------
__global__ __launch_bounds__(256, 4) void attn8(const __bf16* __restrict__ qkv,
                                                const __bf16* __restrict__ vt,
                                                __bf16* __restrict__ y) {
    const int hb = blockIdx.x;                 // fast dim: h + 16*b -> XCD = hb%8
    const int h = hb & 15, b = hb >> 4;
    const int j = blockIdx.y;                  // 0..15
    const int r4 = j & 3, s4 = j >> 2;
    // classes {15,0,8,7} {14,1,9,6} {13,2,10,5} {12,3,11,4}: each sums 30
    const int qt = (s4 == 0) ? 15 - r4 : (s4 == 1) ? r4 : (s4 == 2) ? 8 + r4 : 7 - r4;

    const int tid = threadIdx.x;
    const int wave = tid >> 6, lane = tid & 63;
    const int lrow = lane & 15, quad = lane >> 4;
    const int lm7 = lrow & 7;

    __shared__ __bf16 Klds[2][64 * 64];   // [key][d-chunk8 ^ (key&7)]   2x8 KB
    __shared__ __bf16 Vlds[2][64 * 64];   // [d][k-chunk8 ^ (d&7)]       2x8 KB

    const __bf16* kbase = qkv + (size_t)b * SS * QKV_N + 1024 + h * 64;
    const __bf16* vbase = vt + (size_t)(b * HH + h) * 64 * SS;

    const int qbase = qt * 128;
    // Q fragments (B-operand): q col = lrow; group g -> rows qbase+64g+16w+lrow
    bf16x8 qf[2][2];
#pragma unroll
    for (int g = 0; g < 2; ++g) {
        const __bf16* qp = qkv + (size_t)(b * SS + qbase + 64 * g + wave * 16 + lrow) * QKV_N + h * 64;
        qf[g][0] = *(const bf16x8*)(qp + quad * 8);
        qf[g][1] = *(const bf16x8*)(qp + 32 + quad * 8);
    }
    const int q0 = qbase + wave * 16 + lrow;

    float m[2] = {-INFINITY, -INFINITY};
    float l[2] = {0.f, 0.f};                   // lane-partial row sums
    f32x4 oacc[2][4] = {};   // O^T: d = 16*td + 4*quad + r, q col = lrow

    const int nkv = 2 * qt + 2;                // 64-key blocks
    stage_kv64(kbase, vbase, Klds[0], Vlds[0], 0, tid);   // prime buffer 0

    for (int kk = 0; kk < nkv; ++kk) {
        const int cur = kk & 1;
        const int kb = kk * 64;
        __syncthreads();   // buf[cur] staged; all waves done with buf[cur^1]
        if (kk + 1 < nkv)
            stage_kv64(kbase, vbase, Klds[cur ^ 1], Vlds[cur ^ 1], kb + 64, tid);
        const __bf16* Kb = Klds[cur];
        const __bf16* Vb = Vlds[cur];

        const bool do0 = (kk < nkv - 1);       // last block fully masked for group0
        const bool dg0 = (kk == nkv - 2);      // group0 diagonal block
        const bool dg1 = (kk == nkv - 1);      // group1 diagonal block

        // QK^T: 4 key tiles of 16
        f32x4 s0[4], s1[4];
#pragma unroll
        for (int t = 0; t < 4; ++t) {
            const __bf16* kr = Kb + (16 * t + lrow) * 64;
            bf16x8 kf0 = *(const bf16x8*)(kr + 8 * (quad ^ lm7));
            bf16x8 kf1 = *(const bf16x8*)(kr + 8 * ((4 + quad) ^ lm7));
            f32x4 c1 = {};
            c1 = mfma16(kf0, qf[1][0], c1);
            c1 = mfma16(kf1, qf[1][1], c1);
            s1[t] = c1;
            if (do0) {
                f32x4 c0 = {};
                c0 = mfma16(kf0, qf[0][0], c0);
                c0 = mfma16(kf1, qf[0][1], c0);
                s0[t] = c0;
            }
        }
        if (dg0) {
#pragma unroll
            for (int t = 0; t < 4; ++t)
#pragma unroll
                for (int r = 0; r < 4; ++r)
                    if (kb + 16 * t + 4 * quad + r > q0) s0[t][r] = -INFINITY;
        }
        if (dg1) {
#pragma unroll
            for (int t = 0; t < 4; ++t)
#pragma unroll
                for (int r = 0; r < 4; ++r)
                    if (kb + 16 * t + 4 * quad + r > q0 + 64) s1[t][r] = -INFINITY;
        }

        // online softmax with deferred max (THR=8), per group
        bf16x4 p0[4], p1[4];
#pragma unroll
        for (int g = 0; g < 2; ++g) {
            if (g == 0 && !do0) continue;
            f32x4* s = g ? s1 : s0;
            bf16x4* p = g ? p1 : p0;
            float pmax = -INFINITY;
#pragma unroll
            for (int t = 0; t < 4; ++t)
                pmax = fmaxf(pmax, fmaxf(fmaxf(s[t][0], s[t][1]), fmaxf(s[t][2], s[t][3])));
            // NaN (first iter -inf - -inf) compares false -> triggers rescale
            if (!__all(pmax - m[g] <= 8.0f)) {
                float mr = fmaxf(pmax, __shfl_xor(pmax, 16));
                mr = fmaxf(mr, __shfl_xor(mr, 32));
                float mnew = fmaxf(m[g], mr);
                float alpha = exp2f(m[g] - mnew);
                m[g] = mnew;
                l[g] *= alpha;
#pragma unroll
                for (int td = 0; td < 4; ++td) {
                    oacc[g][td][0] *= alpha; oacc[g][td][1] *= alpha;
                    oacc[g][td][2] *= alpha; oacc[g][td][3] *= alpha;
                }
            }
            const float mg = m[g];
#pragma unroll
            for (int t = 0; t < 4; ++t) {
                float e0 = exp2f(s[t][0] - mg);
                float e1 = exp2f(s[t][1] - mg);
                float e2 = exp2f(s[t][2] - mg);
                float e3 = exp2f(s[t][3] - mg);
                l[g] += (e0 + e1) + (e2 + e3);
                p[t][0] = (__bf16)e0; p[t][1] = (__bf16)e1;
                p[t][2] = (__bf16)e2; p[t][3] = (__bf16)e3;
            }
        }

        // PV: O^T += V^T P^T, K=16 per key tile; V frags shared across groups
#pragma unroll
        for (int t = 0; t < 4; ++t) {
            int klog = 2 * t + (quad >> 1);
            int c8 = klog ^ lm7;
            const __bf16* vcol = Vb + (size_t)lrow * 64 + c8 * 8 + 4 * (quad & 1);
#pragma unroll
            for (int td = 0; td < 4; ++td) {
                bf16x4 vf = *(const bf16x4*)(vcol + td * 16 * 64);
                oacc[1][td] = mfma16k16(vf, p1[t], oacc[1][td]);
                if (do0) oacc[0][td] = mfma16k16(vf, p0[t], oacc[0][td]);
            }
        }
    }

    // epilogue: reduce lane-partial l over quads, then write
#pragma unroll
    for (int g = 0; g < 2; ++g) {
        float lr = l[g];
        lr += __shfl_xor(lr, 16);
        lr += __shfl_xor(lr, 32);
        float linv = 1.f / lr;
        __bf16* yp = y + (size_t)(b * SS + qbase + 64 * g + wave * 16 + lrow) * EE + h * 64;
#pragma unroll
        for (int td = 0; td < 4; ++td) {
            bf16x4 o;
#pragma unroll
            for (int r = 0; r < 4; ++r) o[r] = (__bf16)(oacc[g][td][r] * linv);
            *(bf16x4*)(yp + 16 * td + 4 * quad) = o;
        }
    }
}

// ---------------- launch ----------------
extern "C" void kernel_launch(void* const* d_in, const int* in_sizes, int n_in,
                              void* d_out, int out_size, void* d_ws, size_t ws_size,
                              hipStream_t stream) {
    const float* x      = (const float*)d_in[0];
    const float* w_qkv  = (const float*)d_in[1];
    const float* b_qkv  = (const float*)d_in[2];
    const float* w_proj = (const float*)d_in[3];
    const float* b_proj = (const float*)d_in[4];
    float* out = (float*)d_out;

    __bf16* xb     = (__bf16*)d_ws;                      // 16 MB (reused as vt later)
    __bf16* wqkvT  = xb + (size_t)ROWS * EE;             // [3072][1024]
    __bf16* wprojT = wqkvT + (size_t)QKV_N * EE;         // [1024][1024]
    __bf16* qkv    = wprojT + (size_t)EE * EE;           // [8192][3072]
    __bf16* yb     = qkv + (size_t)ROWS * QKV_N;         // [8192][1024]
    __bf16* vtb    = xb;                                 // alias: xb dead after GEMM1

    cast_f32_bf16<<<dim3(ROWS * EE / 1024), dim3(256), 0, stream>>>(x, xb);
    transpose_cast<<<dim3(QKV_N / 32, EE / 32), dim3(32, 8), 0, stream>>>(w_qkv, wqkvT, EE, QKV_N);
    transpose_cast<<<dim3(EE / 32, EE / 32), dim3(32, 8), 0, stream>>>(w_proj, wprojT, EE, EE);
    // 256x128 tiles: gemm1 grid 32*24=768 (3.0 rounds), gemm2 32*8=256 (1.0)
    gemm8p<true, true><<<dim3((ROWS / 256) * (QKV_N / 128)), dim3(512), 0, stream>>>(
        xb, wqkvT, b_qkv, (void*)qkv, ROWS, QKV_N, EE);
    build_vt<<<dim3(SS / 64, HH, BB), dim3(256), 0, stream>>>(qkv, vtb);
    attn8<<<dim3(HH * BB, NQT), dim3(256), 0, stream>>>(qkv, vtb, yb);
    gemm8p<false, false><<<dim3((ROWS / 256) * (EE / 128)), dim3(512), 0, stream>>>(
        yb, wprojT, b_proj, (void*)out, ROWS, EE, EE);
}

// Round 4
// 283.221 us; speedup vs baseline: 1.0197x; 1.0101x over previous
//
#include <hip/hip_runtime.h>
#include <cmath>
#include <cstdint>

// Shapes (fixed for this problem)
#define BB 4
#define SS 2048
#define EE 1024
#define HH 16
#define DD 64
#define ROWS (BB*SS)          // 8192
#define QKV_N (3*EE)          // 3072
#define NQT64 32              // S / 64 q-tiles

using bf16x8 = __attribute__((ext_vector_type(8))) __bf16;
using bf16x4 = __attribute__((ext_vector_type(4))) __bf16;
using f32x4  = __attribute__((ext_vector_type(4))) float;
typedef __attribute__((ext_vector_type(4))) short short4v;

// log2(e) / sqrt(64): folded into Q columns in the QKV GEMM epilogue
#define SCQ 0.18033688f

__device__ inline f32x4 mfma16(bf16x8 a, bf16x8 b, f32x4 c) {
    return __builtin_amdgcn_mfma_f32_16x16x32_bf16(a, b, c, 0, 0, 0);
}

// K=16 MFMA: B-operand layout (k=4*quad+j, n=lane&15) == C/D layout ->
// exp'd S registers feed PV directly, no cross-lane movement.
__device__ inline f32x4 mfma16k16(bf16x4 a, bf16x4 b, f32x4 c) {
    return __builtin_amdgcn_mfma_f32_16x16x16bf16_1k(
        __builtin_bit_cast(short4v, a), __builtin_bit_cast(short4v, b), c, 0, 0, 0);
}

__device__ inline void load_lds16(const void* g, void* l) {
    __builtin_amdgcn_global_load_lds(
        (__attribute__((address_space(1))) void*)g,
        (__attribute__((address_space(3))) void*)l, 16, 0, 0);
}

// ---------------- cast fp32 -> bf16, vectorized ----------------
__global__ __launch_bounds__(256) void cast_f32_bf16(const float* __restrict__ in,
                                                     __bf16* __restrict__ out) {
    size_t i = ((size_t)blockIdx.x * 256 + threadIdx.x) * 4;
    float4 v = *(const float4*)(in + i);
    bf16x4 o;
    o[0] = (__bf16)v.x; o[1] = (__bf16)v.y; o[2] = (__bf16)v.z; o[3] = (__bf16)v.w;
    *(bf16x4*)(out + i) = o;
}

// ---------------- transpose + cast: in [K][N] f32 -> out [N][K] bf16 ----------------
__global__ __launch_bounds__(256) void transpose_cast(const float* __restrict__ in,
                                                      __bf16* __restrict__ out,
                                                      int K, int N) {
    __shared__ float tile[32][33];
    int n0 = blockIdx.x * 32, k0 = blockIdx.y * 32;
    int tx = threadIdx.x, ty = threadIdx.y;   // block (32,8)
#pragma unroll
    for (int i = 0; i < 4; ++i)
        tile[ty + 8 * i][tx] = in[(size_t)(k0 + ty + 8 * i) * N + n0 + tx];
    __syncthreads();
#pragma unroll
    for (int i = 0; i < 4; ++i)
        out[(size_t)(n0 + ty + 8 * i) * K + k0 + tx] = (__bf16)tile[tx][ty + 8 * i];
}

// ---------------- V transpose: qkv V-section -> vt[b][h][d][s] bf16 ----------------
__global__ __launch_bounds__(256) void build_vt(const __bf16* __restrict__ qkv,
                                                __bf16* __restrict__ vt) {
    __shared__ __bf16 tile[64 * 72];   // [s][d] padded
    const int s0 = blockIdx.x * 64, h = blockIdx.y, b = blockIdx.z;
    const int tid = threadIdx.x;
#pragma unroll
    for (int r = 0; r < 2; ++r) {
        int c = r * 256 + tid;                 // 0..511
        int s = c >> 3, dp = c & 7;
        bf16x8 v = *(const bf16x8*)(qkv + (size_t)(b * SS + s0 + s) * QKV_N + 2048 + h * 64 + dp * 8);
        *(bf16x8*)(tile + s * 72 + dp * 8) = v;
    }
    __syncthreads();
#pragma unroll
    for (int r = 0; r < 2; ++r) {
        int c = r * 256 + tid;
        int d = c >> 3, sp = c & 7;
        bf16x8 o;
#pragma unroll
        for (int i = 0; i < 8; ++i) o[i] = tile[(sp * 8 + i) * 72 + d];
        *(bf16x8*)(vt + (size_t)((b * HH + h) * 64 + d) * SS + s0 + sp * 8) = o;
    }
}

// ---------------- GEMM: C[M][N] = A[M][K] @ Bt[N][K]^T + bias (R1-proven) ----------
// QSCALE: multiply columns [0,EE) by SCQ (folds attention scale into Q).
template <bool OUT_BF16, bool QSCALE>
__global__ __launch_bounds__(256) void gemm_bt(const __bf16* __restrict__ A,
                                               const __bf16* __restrict__ Bt,
                                               const float* __restrict__ bias,
                                               void* __restrict__ Cout,
                                               int M, int N, int K) {
    __shared__ __bf16 As[128 * 32];
    __shared__ __bf16 Bs[128 * 32];
    const int tid  = threadIdx.x;
    const int wave = tid >> 6;
    const int lane = tid & 63;
    const int lrow = lane & 15;
    const int quad = lane >> 4;
    const int wm   = (wave >> 1) * 64;
    const int wn   = (wave & 1) * 64;
    const int tm   = blockIdx.x * 128;
    const int tn   = blockIdx.y * 128;

    f32x4 acc[4][4] = {};

    const int srow = lane >> 2;
    const int skoff = (lane & 3) * 8;

    for (int k0 = 0; k0 < K; k0 += 32) {
        __syncthreads();
#pragma unroll
        for (int i = 0; i < 2; ++i) {
            int c = wave * 2 + i;
            int row = 16 * c + srow;
            load_lds16(A + (size_t)(tm + row) * K + k0 + skoff, As + c * 512);
            load_lds16(Bt + (size_t)(tn + row) * K + k0 + skoff, Bs + c * 512);
        }
        __syncthreads();

        bf16x8 bfr[4];
#pragma unroll
        for (int ni = 0; ni < 4; ++ni)
            bfr[ni] = *(const bf16x8*)(Bs + (wn + ni * 16 + lrow) * 32 + quad * 8);
#pragma unroll
        for (int mi = 0; mi < 4; ++mi) {
            bf16x8 a = *(const bf16x8*)(As + (wm + mi * 16 + lrow) * 32 + quad * 8);
#pragma unroll
            for (int ni = 0; ni < 4; ++ni)
                acc[mi][ni] = mfma16(a, bfr[ni], acc[mi][ni]);
        }
    }

#pragma unroll
    for (int ni = 0; ni < 4; ++ni) {
        int cn = tn + wn + ni * 16 + lrow;
        float bv = bias[cn];
        float sc = (QSCALE && cn < EE) ? SCQ : 1.0f;
#pragma unroll
        for (int mi = 0; mi < 4; ++mi) {
#pragma unroll
            for (int r = 0; r < 4; ++r) {
                int gm = tm + wm + mi * 16 + quad * 4 + r;
                float v = (acc[mi][ni][r] + bv) * sc;
                if (OUT_BF16)
                    ((__bf16*)Cout)[(size_t)gm * N + cn] = (__bf16)v;
                else
                    ((float*)Cout)[(size_t)gm * N + cn] = v;
            }
        }
    }
}

// stage one 64-key K tile + V^T tile into the given LDS buffers (XOR-swizzled
// via pre-swizzled GLOBAL source, LDS dest linear per global_load_lds rules)
__device__ __forceinline__ void stage_kv64(const __bf16* __restrict__ kbase,
                                           const __bf16* __restrict__ vbase,
                                           __bf16* Kb, __bf16* Vb, int kb, int tid) {
#pragma unroll
    for (int r = 0; r < 2; ++r) {          // K: 64 rows x 64 d
        int c = r * 256 + tid;
        int row = c >> 3;
        int g8 = ((c & 7) ^ (row & 7)) * 8;
        load_lds16(kbase + (size_t)(kb + row) * QKV_N + g8, Kb + c * 8);
    }
#pragma unroll
    for (int r = 0; r < 2; ++r) {          // V^T: 64 d-rows x 64 keys
        int c = r * 256 + tid;
        int d = c >> 3, kc = c & 7;
        int g8 = (kc ^ (d & 7)) * 8;
        load_lds16(vbase + (size_t)d * SS + kb + g8, Vb + c * 8);
    }
}

// ---------------- Flash attention v9 ----------------
// v8 -> v9: equal-LENGTH blocks. v8's 4 co-resident blocks/CU had balanced
// total work but lengths 1..16 iterations -> short blocks retire early,
// time-avg residency ~9.4/32 waves, VALUBusy stuck at 66% (occupancy 29.5%).
// v9: 64-row q-tiles (32 of them), each block pairs qtA=31-j with qtB=j ->
// EVERY block runs exactly 33 KV-iterations. grid (64,16)=1024 = 4 blocks/CU,
// LDS 32 KB unchanged, XCD = id%8 = hb%8 preserved. One 16-row group per wave
// per segment (K/V frags no longer shared by 2 groups: 2x LDS reads, still
// under the VALU floor). Residency flat 16 waves/CU.
__global__ __launch_bounds__(256, 4) void attn9(const __bf16* __restrict__ qkv,
                                                const __bf16* __restrict__ vt,
                                                __bf16* __restrict__ y) {
    const int hb = blockIdx.x;                 // fast dim: h + 16*b -> XCD = hb%8
    const int h = hb & 15, b = hb >> 4;
    const int j = blockIdx.y;                  // 0..15

    const int tid = threadIdx.x;
    const int wave = tid >> 6, lane = tid & 63;
    const int lrow = lane & 15, quad = lane >> 4;
    const int lm7 = lrow & 7;

    __shared__ __bf16 Klds[2][64 * 64];   // [key][d-chunk8 ^ (key&7)]   2x8 KB
    __shared__ __bf16 Vlds[2][64 * 64];   // [d][k-chunk8 ^ (d&7)]       2x8 KB

    const __bf16* kbase = qkv + (size_t)b * SS * QKV_N + 1024 + h * 64;
    const __bf16* vbase = vt + (size_t)(b * HH + h) * 64 * SS;

    const int qtA = NQT64 - 1 - j, qtB = j;    // 64-row tiles; lengths 32-j, j+1
    const int nA = qtA + 1, total = nA + qtB + 1;   // == 33 for every block

    stage_kv64(kbase, vbase, Klds[0], Vlds[0], 0, tid);   // prime buffer 0

    int it = 0;
    for (int seg = 0; seg < 2; ++seg) {
        const int qt = seg ? qtB : qtA;
        const int qbase = qt * 64;
        const int qrow = qbase + wave * 16 + lrow;   // this lane's q-row (col in S)
        // Q fragments (B-operand): q col = lrow
        const __bf16* qp = qkv + (size_t)(b * SS + qrow) * QKV_N + h * 64;
        bf16x8 qf0 = *(const bf16x8*)(qp + quad * 8);
        bf16x8 qf1 = *(const bf16x8*)(qp + 32 + quad * 8);

        float m = -INFINITY;
        float l = 0.f;                         // lane-partial row sum
        f32x4 oacc[4] = {};                    // O^T: d = 16*td + 4*quad + r, q col = lrow

        for (int kb_i = 0; kb_i <= qt; ++kb_i, ++it) {
            const int cur = it & 1;
            const int kb = kb_i * 64;
            const bool dg = (kb_i == qt);
            __syncthreads();   // buf[cur] staged; all waves done with buf[cur^1]
            if (it + 1 < total) {
                int nit = it + 1;
                int nkb = (nit < nA ? nit : nit - nA) * 64;
                stage_kv64(kbase, vbase, Klds[cur ^ 1], Vlds[cur ^ 1], nkb, tid);
            }
            const __bf16* Kb = Klds[cur];
            const __bf16* Vb = Vlds[cur];

            // QK^T: 4 key tiles of 16 (key = kb + 16t + 4quad + r, q col = lrow)
            f32x4 s[4];
#pragma unroll
            for (int t = 0; t < 4; ++t) {
                const __bf16* kr = Kb + (16 * t + lrow) * 64;
                bf16x8 kf0 = *(const bf16x8*)(kr + 8 * (quad ^ lm7));
                bf16x8 kf1 = *(const bf16x8*)(kr + 8 * ((4 + quad) ^ lm7));
                f32x4 c = {};
                c = mfma16(kf0, qf0, c);
                c = mfma16(kf1, qf1, c);
                s[t] = c;
            }
            if (dg) {
#pragma unroll
                for (int t = 0; t < 4; ++t)
#pragma unroll
                    for (int r = 0; r < 4; ++r)
                        if (kb + 16 * t + 4 * quad + r > qrow) s[t][r] = -INFINITY;
            }

            // online softmax with deferred max (THR=8)
            float pmax = -INFINITY;
#pragma unroll
            for (int t = 0; t < 4; ++t)
                pmax = fmaxf(pmax, fmaxf(fmaxf(s[t][0], s[t][1]), fmaxf(s[t][2], s[t][3])));
            // NaN / first-iter +inf compares false -> triggers rescale
            if (!__all(pmax - m <= 8.0f)) {
                float mr = fmaxf(pmax, __shfl_xor(pmax, 16));
                mr = fmaxf(mr, __shfl_xor(mr, 32));
                float mnew = fmaxf(m, mr);
                float alpha = exp2f(m - mnew);
                m = mnew;
                l *= alpha;
#pragma unroll
                for (int td = 0; td < 4; ++td) {
                    oacc[td][0] *= alpha; oacc[td][1] *= alpha;
                    oacc[td][2] *= alpha; oacc[td][3] *= alpha;
                }
            }
            bf16x4 p[4];
#pragma unroll
            for (int t = 0; t < 4; ++t) {
                float e0 = exp2f(s[t][0] - m);
                float e1 = exp2f(s[t][1] - m);
                float e2 = exp2f(s[t][2] - m);
                float e3 = exp2f(s[t][3] - m);
                l += (e0 + e1) + (e2 + e3);
                p[t][0] = (__bf16)e0; p[t][1] = (__bf16)e1;
                p[t][2] = (__bf16)e2; p[t][3] = (__bf16)e3;
            }

            // PV: O^T += V^T P^T, K=16 per key tile
#pragma unroll
            for (int t = 0; t < 4; ++t) {
                int klog = 2 * t + (quad >> 1);
                int c8 = klog ^ lm7;
                const __bf16* vcol = Vb + (size_t)lrow * 64 + c8 * 8 + 4 * (quad & 1);
#pragma unroll
                for (int td = 0; td < 4; ++td) {
                    bf16x4 vf = *(const bf16x4*)(vcol + td * 16 * 64);
                    oacc[td] = mfma16k16(vf, p[t], oacc[td]);
                }
            }
        }

        // epilogue: reduce lane-partial l over quads, then write this wave's 16 rows
        float lr = l;
        lr += __shfl_xor(lr, 16);
        lr += __shfl_xor(lr, 32);
        float linv = 1.f / lr;
        __bf16* yp = y + (size_t)(b * SS + qrow) * EE + h * 64;
#pragma unroll
        for (int td = 0; td < 4; ++td) {
            bf16x4 o;
#pragma unroll
            for (int r = 0; r < 4; ++r) o[r] = (__bf16)(oacc[td][r] * linv);
            *(bf16x4*)(yp + 16 * td + 4 * quad) = o;
        }
    }
}

// ---------------- launch ----------------
extern "C" void kernel_launch(void* const* d_in, const int* in_sizes, int n_in,
                              void* d_out, int out_size, void* d_ws, size_t ws_size,
                              hipStream_t stream) {
    const float* x      = (const float*)d_in[0];
    const float* w_qkv  = (const float*)d_in[1];
    const float* b_qkv  = (const float*)d_in[2];
    const float* w_proj = (const float*)d_in[3];
    const float* b_proj = (const float*)d_in[4];
    float* out = (float*)d_out;

    __bf16* xb     = (__bf16*)d_ws;                      // 16 MB (reused as vt later)
    __bf16* wqkvT  = xb + (size_t)ROWS * EE;             // [3072][1024]
    __bf16* wprojT = wqkvT + (size_t)QKV_N * EE;         // [1024][1024]
    __bf16* qkv    = wprojT + (size_t)EE * EE;           // [8192][3072]
    __bf16* yb     = qkv + (size_t)ROWS * QKV_N;         // [8192][1024]
    __bf16* vtb    = xb;                                 // alias: xb dead after GEMM1

    cast_f32_bf16<<<dim3(ROWS * EE / 1024), dim3(256), 0, stream>>>(x, xb);
    transpose_cast<<<dim3(QKV_N / 32, EE / 32), dim3(32, 8), 0, stream>>>(w_qkv, wqkvT, EE, QKV_N);
    transpose_cast<<<dim3(EE / 32, EE / 32), dim3(32, 8), 0, stream>>>(w_proj, wprojT, EE, EE);
    gemm_bt<true, true><<<dim3(ROWS / 128, QKV_N / 128), dim3(256), 0, stream>>>(
        xb, wqkvT, b_qkv, (void*)qkv, ROWS, QKV_N, EE);
    build_vt<<<dim3(SS / 64, HH, BB), dim3(256), 0, stream>>>(qkv, vtb);
    attn9<<<dim3(HH * BB, NQT64 / 2), dim3(256), 0, stream>>>(qkv, vtb, yb);
    gemm_bt<false, false><<<dim3(ROWS / 128, EE / 128), dim3(256), 0, stream>>>(
        yb, wprojT, b_proj, (void*)out, ROWS, EE, EE);
}

// Round 6
// 278.854 us; speedup vs baseline: 1.0357x; 1.0157x over previous
//
#include <hip/hip_runtime.h>
#include <cmath>
#include <cstdint>

// Shapes (fixed for this problem)
#define BB 4
#define SS 2048
#define EE 1024
#define HH 16
#define DD 64
#define ROWS (BB*SS)          // 8192
#define QKV_N (3*EE)          // 3072
#define NQT 16                // S / 128 q-tiles

using bf16x8 = __attribute__((ext_vector_type(8))) __bf16;
using bf16x4 = __attribute__((ext_vector_type(4))) __bf16;
using f32x4  = __attribute__((ext_vector_type(4))) float;
typedef __attribute__((ext_vector_type(4))) short short4v;

// log2(e) / sqrt(64): folded into Q columns in the QKV GEMM epilogue
#define SCQ 0.18033688f

__device__ inline f32x4 mfma16(bf16x8 a, bf16x8 b, f32x4 c) {
    return __builtin_amdgcn_mfma_f32_16x16x32_bf16(a, b, c, 0, 0, 0);
}

// K=16 MFMA: B-operand layout (k=4*quad+j, n=lane&15) == C/D layout ->
// exp'd S registers feed PV directly, no cross-lane movement.
__device__ inline f32x4 mfma16k16(bf16x4 a, bf16x4 b, f32x4 c) {
    return __builtin_amdgcn_mfma_f32_16x16x16bf16_1k(
        __builtin_bit_cast(short4v, a), __builtin_bit_cast(short4v, b), c, 0, 0, 0);
}

__device__ inline void load_lds16(const void* g, void* l) {
    __builtin_amdgcn_global_load_lds(
        (__attribute__((address_space(1))) void*)g,
        (__attribute__((address_space(3))) void*)l, 16, 0, 0);
}

__device__ inline f32x4 max4(f32x4 a, f32x4 b) {
    f32x4 r;
    r[0] = fmaxf(a[0], b[0]); r[1] = fmaxf(a[1], b[1]);
    r[2] = fmaxf(a[2], b[2]); r[3] = fmaxf(a[3], b[3]);
    return r;
}

// ---------------- fused prep: cast x + transpose both weights (1 launch, was 3) ----
// blocks [0,8192): cast x f32->bf16 (4 elems/thread)
// blocks [8192,11264): transpose+cast w_qkv [1024][3072] -> [3072][1024]
// blocks [11264,12288): transpose+cast w_proj [1024][1024] -> [1024][1024]
// Branch is blockIdx-uniform -> __syncthreads in transpose path is safe.
__global__ __launch_bounds__(256) void prep(const float* __restrict__ x,
                                            __bf16* __restrict__ xb,
                                            const float* __restrict__ w_qkv,
                                            __bf16* __restrict__ wqkvT,
                                            const float* __restrict__ w_proj,
                                            __bf16* __restrict__ wprojT) {
    const int bid = blockIdx.x;
    if (bid < 8192) {
        size_t i = ((size_t)bid * 256 + threadIdx.x) * 4;
        float4 v = *(const float4*)(x + i);
        bf16x4 o;
        o[0] = (__bf16)v.x; o[1] = (__bf16)v.y; o[2] = (__bf16)v.z; o[3] = (__bf16)v.w;
        *(bf16x4*)(xb + i) = o;
        return;
    }
    __shared__ float tile[32][33];
    const float* in; __bf16* out; int N, n0, k0;
    if (bid < 8192 + 3072) {
        int idx = bid - 8192;
        in = w_qkv; out = wqkvT; N = QKV_N;
        n0 = (idx % 96) * 32; k0 = (idx / 96) * 32;
    } else {
        int idx = bid - 8192 - 3072;
        in = w_proj; out = wprojT; N = EE;
        n0 = (idx & 31) * 32; k0 = (idx >> 5) * 32;
    }
    const int tx = threadIdx.x & 31, ty = threadIdx.x >> 5;
#pragma unroll
    for (int i = 0; i < 4; ++i)
        tile[ty + 8 * i][tx] = in[(size_t)(k0 + ty + 8 * i) * N + n0 + tx];
    __syncthreads();
#pragma unroll
    for (int i = 0; i < 4; ++i)
        out[(size_t)(n0 + ty + 8 * i) * EE + k0 + tx] = (__bf16)tile[tx][ty + 8 * i];
}

// ---------------- V transpose: qkv V-section -> vt[b][h][d][s] bf16 ----------------
__global__ __launch_bounds__(256) void build_vt(const __bf16* __restrict__ qkv,
                                                __bf16* __restrict__ vt) {
    __shared__ __bf16 tile[64 * 72];   // [s][d] padded
    const int s0 = blockIdx.x * 64, h = blockIdx.y, b = blockIdx.z;
    const int tid = threadIdx.x;
#pragma unroll
    for (int r = 0; r < 2; ++r) {
        int c = r * 256 + tid;                 // 0..511
        int s = c >> 3, dp = c & 7;
        bf16x8 v = *(const bf16x8*)(qkv + (size_t)(b * SS + s0 + s) * QKV_N + 2048 + h * 64 + dp * 8);
        *(bf16x8*)(tile + s * 72 + dp * 8) = v;
    }
    __syncthreads();
#pragma unroll
    for (int r = 0; r < 2; ++r) {
        int c = r * 256 + tid;
        int d = c >> 3, sp = c & 7;
        bf16x8 o;
#pragma unroll
        for (int i = 0; i < 8; ++i) o[i] = tile[(sp * 8 + i) * 72 + d];
        *(bf16x8*)(vt + (size_t)((b * HH + h) * 64 + d) * SS + s0 + sp * 8) = o;
    }
}

// ---------------- GEMM: C[M][N] = A[M][K] @ Bt[N][K]^T + bias (R1-proven) ----------
template <bool OUT_BF16, bool QSCALE>
__global__ __launch_bounds__(256) void gemm_bt(const __bf16* __restrict__ A,
                                               const __bf16* __restrict__ Bt,
                                               const float* __restrict__ bias,
                                               void* __restrict__ Cout,
                                               int M, int N, int K) {
    __shared__ __bf16 As[128 * 32];
    __shared__ __bf16 Bs[128 * 32];
    const int tid  = threadIdx.x;
    const int wave = tid >> 6;
    const int lane = tid & 63;
    const int lrow = lane & 15;
    const int quad = lane >> 4;
    const int wm   = (wave >> 1) * 64;
    const int wn   = (wave & 1) * 64;
    const int tm   = blockIdx.x * 128;
    const int tn   = blockIdx.y * 128;

    f32x4 acc[4][4] = {};

    const int srow = lane >> 2;
    const int skoff = (lane & 3) * 8;

    for (int k0 = 0; k0 < K; k0 += 32) {
        __syncthreads();
#pragma unroll
        for (int i = 0; i < 2; ++i) {
            int c = wave * 2 + i;
            int row = 16 * c + srow;
            load_lds16(A + (size_t)(tm + row) * K + k0 + skoff, As + c * 512);
            load_lds16(Bt + (size_t)(tn + row) * K + k0 + skoff, Bs + c * 512);
        }
        __syncthreads();

        bf16x8 bfr[4];
#pragma unroll
        for (int ni = 0; ni < 4; ++ni)
            bfr[ni] = *(const bf16x8*)(Bs + (wn + ni * 16 + lrow) * 32 + quad * 8);
#pragma unroll
        for (int mi = 0; mi < 4; ++mi) {
            bf16x8 a = *(const bf16x8*)(As + (wm + mi * 16 + lrow) * 32 + quad * 8);
#pragma unroll
            for (int ni = 0; ni < 4; ++ni)
                acc[mi][ni] = mfma16(a, bfr[ni], acc[mi][ni]);
        }
    }

#pragma unroll
    for (int ni = 0; ni < 4; ++ni) {
        int cn = tn + wn + ni * 16 + lrow;
        float bv = bias[cn];
        float sc = (QSCALE && cn < EE) ? SCQ : 1.0f;
#pragma unroll
        for (int mi = 0; mi < 4; ++mi) {
#pragma unroll
            for (int r = 0; r < 4; ++r) {
                int gm = tm + wm + mi * 16 + quad * 4 + r;
                float v = (acc[mi][ni][r] + bv) * sc;
                if (OUT_BF16)
                    ((__bf16*)Cout)[(size_t)gm * N + cn] = (__bf16)v;
                else
                    ((float*)Cout)[(size_t)gm * N + cn] = v;
            }
        }
    }
}

// stage one 64-key K tile + V^T tile into the given LDS buffers (XOR-swizzled
// via pre-swizzled GLOBAL source, LDS dest linear per global_load_lds rules)
__device__ __forceinline__ void stage_kv64(const __bf16* __restrict__ kbase,
                                           const __bf16* __restrict__ vbase,
                                           __bf16* Kb, __bf16* Vb, int kb, int tid) {
#pragma unroll
    for (int r = 0; r < 2; ++r) {          // K: 64 rows x 64 d
        int c = r * 256 + tid;
        int row = c >> 3;
        int g8 = ((c & 7) ^ (row & 7)) * 8;
        load_lds16(kbase + (size_t)(kb + row) * QKV_N + g8, Kb + c * 8);
    }
#pragma unroll
    for (int r = 0; r < 2; ++r) {          // V^T: 64 d-rows x 64 keys
        int c = r * 256 + tid;
        int d = c >> 3, kc = c & 7;
        int g8 = (kc ^ (d & 7)) * 8;
        load_lds16(vbase + (size_t)d * SS + kb + g8, Vb + c * 8);
    }
}

// ---------------- Flash attention v10 = v8 structure + vector softmax ----------
// R5 post-mortem: attn10 failed because the group-1 diagonal mask used v7's
// 128-key-tile form (kb + 64 + ...) instead of v8's 64-key form (kb + ...),
// over-masking keys (q0, q0+64] for group 1. Fixed to the R1-verified line.
// Rest is R5's intent: v8 2-group structure + softmax in f32x4 vector form
// (sub / l-sum / rescale packed; l lane-partial f32x4, folded in epilogue).
__global__ __launch_bounds__(256, 4) void attn10(const __bf16* __restrict__ qkv,
                                                 const __bf16* __restrict__ vt,
                                                 __bf16* __restrict__ y) {
    const int hb = blockIdx.x;                 // fast dim: h + 16*b -> XCD = hb%8
    const int h = hb & 15, b = hb >> 4;
    const int j = blockIdx.y;                  // 0..15
    const int r4 = j & 3, s4 = j >> 2;
    // classes {15,0,8,7} {14,1,9,6} {13,2,10,5} {12,3,11,4}: each sums 30
    const int qt = (s4 == 0) ? 15 - r4 : (s4 == 1) ? r4 : (s4 == 2) ? 8 + r4 : 7 - r4;

    const int tid = threadIdx.x;
    const int wave = tid >> 6, lane = tid & 63;
    const int lrow = lane & 15, quad = lane >> 4;
    const int lm7 = lrow & 7;

    __shared__ __bf16 Klds[2][64 * 64];   // [key][d-chunk8 ^ (key&7)]   2x8 KB
    __shared__ __bf16 Vlds[2][64 * 64];   // [d][k-chunk8 ^ (d&7)]       2x8 KB

    const __bf16* kbase = qkv + (size_t)b * SS * QKV_N + 1024 + h * 64;
    const __bf16* vbase = vt + (size_t)(b * HH + h) * 64 * SS;

    const int qbase = qt * 128;
    // Q fragments (B-operand): q col = lrow; group g -> rows qbase+64g+16w+lrow
    bf16x8 qf[2][2];
#pragma unroll
    for (int g = 0; g < 2; ++g) {
        const __bf16* qp = qkv + (size_t)(b * SS + qbase + 64 * g + wave * 16 + lrow) * QKV_N + h * 64;
        qf[g][0] = *(const bf16x8*)(qp + quad * 8);
        qf[g][1] = *(const bf16x8*)(qp + 32 + quad * 8);
    }
    const int q0 = qbase + wave * 16 + lrow;

    float m[2] = {-INFINITY, -INFINITY};
    f32x4 lacc[2] = {};                        // lane-partial row sums (vector)
    f32x4 oacc[2][4] = {};   // O^T: d = 16*td + 4*quad + r, q col = lrow

    const int nkv = 2 * qt + 2;                // 64-key blocks
    stage_kv64(kbase, vbase, Klds[0], Vlds[0], 0, tid);   // prime buffer 0

    for (int kk = 0; kk < nkv; ++kk) {
        const int cur = kk & 1;
        const int kb = kk * 64;
        __syncthreads();   // buf[cur] staged; all waves done with buf[cur^1]
        if (kk + 1 < nkv)
            stage_kv64(kbase, vbase, Klds[cur ^ 1], Vlds[cur ^ 1], kb + 64, tid);
        const __bf16* Kb = Klds[cur];
        const __bf16* Vb = Vlds[cur];

        const bool do0 = (kk < nkv - 1);       // last block fully masked for group0
        const bool dg0 = (kk == nkv - 2);      // group0 diagonal block
        const bool dg1 = (kk == nkv - 1);      // group1 diagonal block

        // QK^T: 4 key tiles of 16
        f32x4 s0[4], s1[4];
#pragma unroll
        for (int t = 0; t < 4; ++t) {
            const __bf16* kr = Kb + (16 * t + lrow) * 64;
            bf16x8 kf0 = *(const bf16x8*)(kr + 8 * (quad ^ lm7));
            bf16x8 kf1 = *(const bf16x8*)(kr + 8 * ((4 + quad) ^ lm7));
            f32x4 c1 = {};
            c1 = mfma16(kf0, qf[1][0], c1);
            c1 = mfma16(kf1, qf[1][1], c1);
            s1[t] = c1;
            if (do0) {
                f32x4 c0 = {};
                c0 = mfma16(kf0, qf[0][0], c0);
                c0 = mfma16(kf1, qf[0][1], c0);
                s0[t] = c0;
            }
        }
        if (dg0) {
#pragma unroll
            for (int t = 0; t < 4; ++t)
#pragma unroll
                for (int r = 0; r < 4; ++r)
                    if (kb + 16 * t + 4 * quad + r > q0) s0[t][r] = -INFINITY;
        }
        if (dg1) {
#pragma unroll
            for (int t = 0; t < 4; ++t)
#pragma unroll
                for (int r = 0; r < 4; ++r)
                    if (kb + 16 * t + 4 * quad + r > q0 + 64) s1[t][r] = -INFINITY;
        }

        // online softmax with deferred max (THR=8), per group — vector form
        bf16x4 p0[4], p1[4];
#pragma unroll
        for (int g = 0; g < 2; ++g) {
            if (g == 0 && !do0) continue;
            f32x4* s = g ? s1 : s0;
            bf16x4* p = g ? p1 : p0;
            f32x4 m03 = max4(max4(s[0], s[1]), max4(s[2], s[3]));
            float pmax = fmaxf(fmaxf(m03[0], m03[1]), fmaxf(m03[2], m03[3]));
            // NaN (first iter -inf - -inf) compares false -> triggers rescale
            if (!__all(pmax - m[g] <= 8.0f)) {
                float mr = fmaxf(pmax, __shfl_xor(pmax, 16));
                mr = fmaxf(mr, __shfl_xor(mr, 32));
                float mnew = fmaxf(m[g], mr);
                float alpha = exp2f(m[g] - mnew);
                m[g] = mnew;
                lacc[g] *= alpha;
#pragma unroll
                for (int td = 0; td < 4; ++td) oacc[g][td] *= alpha;
            }
            const float mg = m[g];
            const f32x4 mgv = {mg, mg, mg, mg};
#pragma unroll
            for (int t = 0; t < 4; ++t) {
                f32x4 d = s[t] - mgv;          // packed-f32 candidates
                f32x4 e;
                e[0] = exp2f(d[0]); e[1] = exp2f(d[1]);
                e[2] = exp2f(d[2]); e[3] = exp2f(d[3]);
                lacc[g] += e;
                p[t][0] = (__bf16)e[0]; p[t][1] = (__bf16)e[1];
                p[t][2] = (__bf16)e[2]; p[t][3] = (__bf16)e[3];
            }
        }

        // PV: O^T += V^T P^T, K=16 per key tile; V frags shared across groups
#pragma unroll
        for (int t = 0; t < 4; ++t) {
            int klog = 2 * t + (quad >> 1);
            int c8 = klog ^ lm7;
            const __bf16* vcol = Vb + (size_t)lrow * 64 + c8 * 8 + 4 * (quad & 1);
#pragma unroll
            for (int td = 0; td < 4; ++td) {
                bf16x4 vf = *(const bf16x4*)(vcol + td * 16 * 64);
                oacc[1][td] = mfma16k16(vf, p1[t], oacc[1][td]);
                if (do0) oacc[0][td] = mfma16k16(vf, p0[t], oacc[0][td]);
            }
        }
    }

    // epilogue: fold vector l, reduce over quads, write
#pragma unroll
    for (int g = 0; g < 2; ++g) {
        float lr = (lacc[g][0] + lacc[g][1]) + (lacc[g][2] + lacc[g][3]);
        lr += __shfl_xor(lr, 16);
        lr += __shfl_xor(lr, 32);
        float linv = 1.f / lr;
        __bf16* yp = y + (size_t)(b * SS + qbase + 64 * g + wave * 16 + lrow) * EE + h * 64;
#pragma unroll
        for (int td = 0; td < 4; ++td) {
            bf16x4 o;
#pragma unroll
            for (int r = 0; r < 4; ++r) o[r] = (__bf16)(oacc[g][td][r] * linv);
            *(bf16x4*)(yp + 16 * td + 4 * quad) = o;
        }
    }
}

// ---------------- launch ----------------
extern "C" void kernel_launch(void* const* d_in, const int* in_sizes, int n_in,
                              void* d_out, int out_size, void* d_ws, size_t ws_size,
                              hipStream_t stream) {
    const float* x      = (const float*)d_in[0];
    const float* w_qkv  = (const float*)d_in[1];
    const float* b_qkv  = (const float*)d_in[2];
    const float* w_proj = (const float*)d_in[3];
    const float* b_proj = (const float*)d_in[4];
    float* out = (float*)d_out;

    __bf16* xb     = (__bf16*)d_ws;                      // 16 MB (reused as vt later)
    __bf16* wqkvT  = xb + (size_t)ROWS * EE;             // [3072][1024]
    __bf16* wprojT = wqkvT + (size_t)QKV_N * EE;         // [1024][1024]
    __bf16* qkv    = wprojT + (size_t)EE * EE;           // [8192][3072]
    __bf16* yb     = qkv + (size_t)ROWS * QKV_N;         // [8192][1024]
    __bf16* vtb    = xb;                                 // alias: xb dead after GEMM1

    prep<<<dim3(8192 + 3072 + 1024), dim3(256), 0, stream>>>(
        x, xb, w_qkv, wqkvT, w_proj, wprojT);
    gemm_bt<true, true><<<dim3(ROWS / 128, QKV_N / 128), dim3(256), 0, stream>>>(
        xb, wqkvT, b_qkv, (void*)qkv, ROWS, QKV_N, EE);
    build_vt<<<dim3(SS / 64, HH, BB), dim3(256), 0, stream>>>(qkv, vtb);
    attn10<<<dim3(HH * BB, NQT), dim3(256), 0, stream>>>(qkv, vtb, yb);
    gemm_bt<false, false><<<dim3(ROWS / 128, EE / 128), dim3(256), 0, stream>>>(
        yb, wprojT, b_proj, (void*)out, ROWS, EE, EE);
}